// Round 5
// baseline (358.741 us; speedup 1.0000x reference)
//
#include <hip/hip_runtime.h>

#define VN 49152
#define DEG 20
#define NB 2
#define MROWS (NB * VN)   // 98304 rows

static constexpr float BN_EPS = 1e-5f;

typedef short bf16x8 __attribute__((ext_vector_type(8)));
typedef float floatx4 __attribute__((ext_vector_type(4)));

__device__ __forceinline__ unsigned short f2bf(float f) {
  unsigned int u = __builtin_bit_cast(unsigned int, f);
  u += 0x7FFFu + ((u >> 16) & 1u);            // RNE
  return (unsigned short)(u >> 16);
}
__device__ __forceinline__ float bf2f(unsigned short h) {
  unsigned int u = ((unsigned int)h) << 16;
  return __builtin_bit_cast(float, u);
}
// packed-bf16 tricks: 1 VALU per element
__device__ __forceinline__ float bflo(unsigned int u) {
  return __builtin_bit_cast(float, u << 16);
}
__device__ __forceinline__ float bfhi(unsigned int u) {
  return __builtin_bit_cast(float, u & 0xFFFF0000u);
}
__device__ __forceinline__ unsigned int packbf(float a, float b) {
  return (unsigned int)f2bf(a) | ((unsigned int)f2bf(b) << 16);
}

// Per-channel BN scale/shift recomputed by CONSUMERS from gsum partials.
// gsum layout: [0..S-1] = channel sums, [S..2S-1] = channel sumsq.
__device__ __forceinline__ void scsh_from(const float* __restrict__ gsum,
    const float* __restrict__ gamma, const float* __restrict__ beta,
    int c, int S, float& sc, float& sh) {
  float mean = gsum[c] * (1.f / MROWS);
  float var  = gsum[S + c] * (1.f / MROWS) - mean * mean;
  sc = gamma[c] * rsqrtf(var + BN_EPS);
  sh = beta[c] - mean * sc;
}

// Feature planes (64-ch) are stored SWIZZLED as 4 sub-planes
// [batch][chalf][VN][32]: addr(b,v,ch) = ((b*2 + ch/32)*VN + v)*32 + ch%32.
//
// GEMMs use 64-row tiles (M=64): round-3 showed 128-row tiles left the GEMMs
// latency-bound at 32% occupancy (grid ~= residency, no steady state).
// 64-row: LDS/block ~halves -> 8 blocks/CU (gemm2/3), grids double.
// Epilogues transpose acc through LDS (TRS stride) -> 16 B coalesced stores.
#define TRS 72

// ======================= GEMM1: t1 = x @ W1 + b1 ===========================
#define LDA1 136
__global__ __launch_bounds__(256) void gemm1(const float* __restrict__ X,
    const float* __restrict__ W, const float* __restrict__ bias,
    unsigned short* __restrict__ Y, float* __restrict__ gsum) {
  __shared__ unsigned short As[64 * LDA1];
  __shared__ unsigned short Bs[64 * LDA1];
  __shared__ float sred[128];
  int t = threadIdx.x;
  int row0 = blockIdx.x * 64;
  if (t < 128) sred[t] = 0.f;
  const float* Xt = X + (size_t)row0 * 128;
  #pragma unroll
  for (int c = 0; c < 8; ++c) {
    int f4i = c * 256 + t;              // 0..2047 (64 rows x 32 float4)
    int row = f4i >> 5, k = (f4i & 31) * 4;
    float4 v = *(const float4*)(Xt + row * 128 + k);
    *(uint2*)(&As[row * LDA1 + k]) = make_uint2(packbf(v.x, v.y), packbf(v.z, v.w));
  }
  #pragma unroll
  for (int c = 0; c < 32; ++c) {
    int f = c * 256 + t;                // W1: 128x64
    int k = f >> 6, n = f & 63;
    Bs[n * LDA1 + k] = f2bf(W[f]);
  }
  __syncthreads();
  int l = t & 63, wv = t >> 6;
  int lr = l & 15, q = l >> 4;
  int m0 = wv * 16;                     // wave owns 16 rows
  floatx4 acc[4];
  #pragma unroll
  for (int ni = 0; ni < 4; ++ni) acc[ni] = (floatx4)(0.f);
  #pragma unroll
  for (int ks = 0; ks < 128; ks += 32) {
    bf16x8 af = *(const bf16x8*)(&As[(m0 + lr) * LDA1 + ks + q * 8]);
    bf16x8 bfr[4];
    #pragma unroll
    for (int ni = 0; ni < 4; ++ni)
      bfr[ni] = *(const bf16x8*)(&Bs[(ni * 16 + lr) * LDA1 + ks + q * 8]);
    #pragma unroll
    for (int ni = 0; ni < 4; ++ni)
      acc[ni] = __builtin_amdgcn_mfma_f32_16x16x32_bf16(af, bfr[ni], acc[ni], 0, 0, 0);
  }
  __syncthreads();          // As/Bs reads done; reuse As as Tr[64][TRS]
  int b = (row0 >= VN) ? 1 : 0;
  int b2 = b * 2, vb0 = row0 - b * VN;
  #pragma unroll
  for (int ni = 0; ni < 4; ++ni) {
    int col = ni * 16 + lr;
    float bv = bias[col];
    float s = 0.f, s2 = 0.f;
    #pragma unroll
    for (int r = 0; r < 4; ++r) {
      float y = acc[ni][r] + bv;
      s += y; s2 += y * y;
      As[(m0 + q * 4 + r) * TRS + col] = f2bf(y);
    }
    atomicAdd(&sred[col], s);
    atomicAdd(&sred[64 + col], s2);
  }
  __syncthreads();
  #pragma unroll
  for (int i = 0; i < 2; ++i) {
    int idx = i * 256 + t;              // 0..511 (64 rows x 2 halves x 4 chunks)
    int p = idx >> 8, rem = idx & 255;
    int rowIdx = rem >> 2, ch0 = (rem & 3) * 8;
    uint4 d = *(const uint4*)(&As[rowIdx * TRS + p * 32 + ch0]);
    *(uint4*)(Y + ((size_t)(b2 + p) * VN + vb0 + rowIdx) * 32 + ch0) = d;
  }
  if (t < 128) atomicAdd(&gsum[t], sred[t]);
}

// ---------------- spmm1: x1 = L relu(bn1(t1))  (BN applied inline) ---------
__global__ __launch_bounds__(256) void spmm1(const unsigned short* __restrict__ T1,
    const int* __restrict__ cols, const float* __restrict__ vals,
    const float* __restrict__ gsum, const float* __restrict__ gamma,
    const float* __restrict__ beta, unsigned short* __restrict__ X1out) {
  int g = blockIdx.x;
  int combo = (g & 7) >> 1;
  int rg = ((g >> 3) << 1) | (g & 1);
  int t = threadIdx.x;
  int wv = t >> 6, lane = t & 63;
  int v = rg * 64 + wv * 16 + (lane >> 2);
  int ch0 = (lane & 3) * 8;
  int cb = (combo & 1) * 32 + ch0;
  float sc[8], sh[8];
  #pragma unroll
  for (int j = 0; j < 8; ++j) scsh_from(gsum, gamma, beta, cb + j, 64, sc[j], sh[j]);
  const unsigned short* __restrict__ plane = T1 + (size_t)combo * VN * 32;
  float a[8];
  {
    float w0 = vals[v];
    uint4 d = *(const uint4*)(plane + (size_t)v * 32 + ch0);
    float e[8] = {bflo(d.x), bfhi(d.x), bflo(d.y), bfhi(d.y),
                  bflo(d.z), bfhi(d.z), bflo(d.w), bfhi(d.w)};
    #pragma unroll
    for (int j = 0; j < 8; ++j) {
      float h = fmaf(e[j], sc[j], sh[j]);
      h = h > 0.f ? h : 0.f;
      a[j] = w0 * h;
    }
  }
  const int*   __restrict__ cp = cols + VN + v * DEG;
  const float* __restrict__ vp = vals + VN + v * DEG;
  #pragma unroll
  for (int j = 0; j < DEG; ++j) {
    int cj = cp[j];
    float wj = vp[j];
    uint4 d = *(const uint4*)(plane + (size_t)cj * 32 + ch0);
    float e[8] = {bflo(d.x), bfhi(d.x), bflo(d.y), bfhi(d.y),
                  bflo(d.z), bfhi(d.z), bflo(d.w), bfhi(d.w)};
    #pragma unroll
    for (int i = 0; i < 8; ++i) {
      float h = fmaf(e[i], sc[i], sh[i]);
      h = h > 0.f ? h : 0.f;
      a[i] = fmaf(h, wj, a[i]);
    }
  }
  uint4 o;
  o.x = packbf(a[0], a[1]); o.y = packbf(a[2], a[3]);
  o.z = packbf(a[4], a[5]); o.w = packbf(a[6], a[7]);
  *(uint4*)(X1out + (size_t)combo * VN * 32 + (size_t)v * 32 + ch0) = o;
}

// ------------- spmm2: x2 = 2*(L x1) - relu(bn1(t1)) ------------------------
__global__ __launch_bounds__(256) void spmm2(const unsigned short* __restrict__ X1,
    const unsigned short* __restrict__ T1, const int* __restrict__ cols,
    const float* __restrict__ vals, const float* __restrict__ gsum,
    const float* __restrict__ gamma, const float* __restrict__ beta,
    unsigned short* __restrict__ X2out) {
  int g = blockIdx.x;
  int combo = (g & 7) >> 1;
  int rg = ((g >> 3) << 1) | (g & 1);
  int t = threadIdx.x;
  int wv = t >> 6, lane = t & 63;
  int v = rg * 64 + wv * 16 + (lane >> 2);
  int ch0 = (lane & 3) * 8;
  const size_t pbase = (size_t)combo * VN * 32;
  const size_t myoff = pbase + (size_t)v * 32 + ch0;
  const unsigned short* __restrict__ plane = X1 + pbase;
  float a[8];
  {
    float w0 = vals[v];
    uint4 d = *(const uint4*)(X1 + myoff);
    a[0] = w0 * bflo(d.x); a[1] = w0 * bfhi(d.x);
    a[2] = w0 * bflo(d.y); a[3] = w0 * bfhi(d.y);
    a[4] = w0 * bflo(d.z); a[5] = w0 * bfhi(d.z);
    a[6] = w0 * bflo(d.w); a[7] = w0 * bfhi(d.w);
  }
  const int*   __restrict__ cp = cols + VN + v * DEG;
  const float* __restrict__ vp = vals + VN + v * DEG;
  #pragma unroll
  for (int j = 0; j < DEG; ++j) {
    int cj = cp[j];
    float wj = vp[j];
    uint4 d = *(const uint4*)(plane + (size_t)cj * 32 + ch0);
    a[0] = fmaf(bflo(d.x), wj, a[0]); a[1] = fmaf(bfhi(d.x), wj, a[1]);
    a[2] = fmaf(bflo(d.y), wj, a[2]); a[3] = fmaf(bfhi(d.y), wj, a[3]);
    a[4] = fmaf(bflo(d.z), wj, a[4]); a[5] = fmaf(bfhi(d.z), wj, a[5]);
    a[6] = fmaf(bflo(d.w), wj, a[6]); a[7] = fmaf(bfhi(d.w), wj, a[7]);
  }
  int cb = (combo & 1) * 32 + ch0;
  float sc[8], sh[8];
  #pragma unroll
  for (int j = 0; j < 8; ++j) scsh_from(gsum, gamma, beta, cb + j, 64, sc[j], sh[j]);
  uint4 hr = *(const uint4*)(T1 + myoff);
  float e[8] = {bflo(hr.x), bfhi(hr.x), bflo(hr.y), bfhi(hr.y),
                bflo(hr.z), bfhi(hr.z), bflo(hr.w), bfhi(hr.w)};
  float oo[8];
  #pragma unroll
  for (int j = 0; j < 8; ++j) {
    float h = fmaf(e[j], sc[j], sh[j]);
    h = h > 0.f ? h : 0.f;
    oo[j] = 2.f * a[j] - h;
  }
  uint4 o;
  o.x = packbf(oo[0], oo[1]); o.y = packbf(oo[2], oo[3]);
  o.z = packbf(oo[4], oo[5]); o.w = packbf(oo[6], oo[7]);
  *(uint4*)(X2out + myoff) = o;
}

// ===== GEMM2: t2 = h1@W2[0] + x1@W2[1] + x2@W2[2] + b2 =====================
// h1 term: bn1+relu applied in A-staging. Y aliases X0 (t2 overwrites t1):
// safe, each block rewrites only the rows it staged, after the barriers.
#define LDA2 72
__global__ __launch_bounds__(256) void gemm2(const unsigned short* X0,
    const unsigned short* __restrict__ X1, const unsigned short* __restrict__ X2,
    const float* __restrict__ W, const float* __restrict__ bias,
    const float* __restrict__ gsumIn, const float* __restrict__ gamma,
    const float* __restrict__ beta, unsigned short* Y,
    float* __restrict__ gsumOut) {
  __shared__ unsigned short As[64 * LDA2];
  __shared__ unsigned short Bs[64 * LDA2];
  __shared__ float sred[128];
  int t = threadIdx.x;
  int row0 = blockIdx.x * 64;
  int b = (row0 >= VN) ? 1 : 0;
  int b2 = b * 2;
  int vb0 = row0 - b * VN;
  if (t < 128) sred[t] = 0.f;
  int kk = (t & 15) * 4;
  int r0 = t >> 4;
  float tsc[4], tsh[4];
  #pragma unroll
  for (int j = 0; j < 4; ++j) scsh_from(gsumIn, gamma, beta, kk + j, 64, tsc[j], tsh[j]);
  int l = t & 63, wv = t >> 6;
  int lr = l & 15, q = l >> 4;
  int m0 = wv * 16;
  floatx4 acc[4];
  #pragma unroll
  for (int ni = 0; ni < 4; ++ni) acc[ni] = (floatx4)(0.f);

  #pragma unroll
  for (int term = 0; term < 3; ++term) {
    const unsigned short* Xp = (term == 0) ? X0 : (term == 1) ? X1 : X2;
    const float* Wt = W + term * 64 * 64;
    const unsigned short* srcBase =
        Xp + ((size_t)(b2 + (kk >> 5)) * VN + vb0) * 32 + (kk & 31);
    #pragma unroll
    for (int c8 = 0; c8 < 4; ++c8) {          // 64 rows, 16 rows/iter
      int row = c8 * 16 + r0;
      uint2 rawv = *(const uint2*)(srcBase + (size_t)row * 32);
      if (term == 0) {
        float y0 = fmaf(bflo(rawv.x), tsc[0], tsh[0]);
        float y1 = fmaf(bfhi(rawv.x), tsc[1], tsh[1]);
        float y2 = fmaf(bflo(rawv.y), tsc[2], tsh[2]);
        float y3 = fmaf(bfhi(rawv.y), tsc[3], tsh[3]);
        y0 = y0 > 0.f ? y0 : 0.f; y1 = y1 > 0.f ? y1 : 0.f;
        y2 = y2 > 0.f ? y2 : 0.f; y3 = y3 > 0.f ? y3 : 0.f;
        *(uint2*)(&As[row * LDA2 + kk]) = make_uint2(packbf(y0, y1), packbf(y2, y3));
      } else {
        *(uint2*)(&As[row * LDA2 + kk]) = rawv;
      }
    }
    #pragma unroll
    for (int c = 0; c < 16; ++c) {
      int f = c * 256 + t;
      int k = f >> 6, n = f & 63;
      Bs[n * LDA2 + k] = f2bf(Wt[f]);
    }
    __syncthreads();
    #pragma unroll
    for (int ks = 0; ks < 64; ks += 32) {
      bf16x8 af = *(const bf16x8*)(&As[(m0 + lr) * LDA2 + ks + q * 8]);
      bf16x8 bfr[4];
      #pragma unroll
      for (int ni = 0; ni < 4; ++ni)
        bfr[ni] = *(const bf16x8*)(&Bs[(ni * 16 + lr) * LDA2 + ks + q * 8]);
      #pragma unroll
      for (int ni = 0; ni < 4; ++ni)
        acc[ni] = __builtin_amdgcn_mfma_f32_16x16x32_bf16(af, bfr[ni], acc[ni], 0, 0, 0);
    }
    __syncthreads();
  }
  // epilogue: transpose through As (reuse, Tr[64][TRS]) -> coalesced stores
  #pragma unroll
  for (int ni = 0; ni < 4; ++ni) {
    int col = ni * 16 + lr;
    float bv = bias[col];
    float s = 0.f, s2 = 0.f;
    #pragma unroll
    for (int r = 0; r < 4; ++r) {
      float y = acc[ni][r] + bv;
      s += y; s2 += y * y;
      As[(m0 + q * 4 + r) * TRS + col] = f2bf(y);
    }
    atomicAdd(&sred[col], s);
    atomicAdd(&sred[64 + col], s2);
  }
  __syncthreads();
  #pragma unroll
  for (int i = 0; i < 2; ++i) {
    int idx = i * 256 + t;
    int p = idx >> 8, rem = idx & 255;
    int rowIdx = rem >> 2, ch0 = (rem & 3) * 8;
    uint4 d = *(const uint4*)(&As[rowIdx * TRS + p * 32 + ch0]);
    *(uint4*)(Y + ((size_t)(b2 + p) * VN + vb0 + rowIdx) * 32 + ch0) = d;
  }
  if (t < 128) atomicAdd(&gsumOut[t], sred[t]);
}

// ====== GEMM3: t3 = relu(bn2(t2)) @ W3 + b3  (two 64-col halves, y-grid) ===
__global__ __launch_bounds__(256) void gemm3(const unsigned short* __restrict__ X,
    const float* __restrict__ W, const float* __restrict__ bias,
    const float* __restrict__ gsumIn, const float* __restrict__ gamma,
    const float* __restrict__ beta, unsigned short* __restrict__ Y,
    float* __restrict__ gsumOut) {
  __shared__ unsigned short As[64 * LDA2];
  __shared__ unsigned short Bs[64 * LDA2];
  __shared__ float sred[128];
  int t = threadIdx.x;
  int row0 = blockIdx.x * 64;
  int n0 = blockIdx.y * 64;
  int b = (row0 >= VN) ? 1 : 0;
  int b2 = b * 2;
  int vb0 = row0 - b * VN;
  if (t < 128) sred[t] = 0.f;
  int kk = (t & 15) * 4;
  int r0 = t >> 4;
  float tsc[4], tsh[4];
  #pragma unroll
  for (int j = 0; j < 4; ++j) scsh_from(gsumIn, gamma, beta, kk + j, 64, tsc[j], tsh[j]);
  const unsigned short* srcBase =
      X + ((size_t)(b2 + (kk >> 5)) * VN + vb0) * 32 + (kk & 31);
  #pragma unroll
  for (int c8 = 0; c8 < 4; ++c8) {
    int row = c8 * 16 + r0;
    uint2 rawv = *(const uint2*)(srcBase + (size_t)row * 32);
    float y0 = fmaf(bflo(rawv.x), tsc[0], tsh[0]);
    float y1 = fmaf(bfhi(rawv.x), tsc[1], tsh[1]);
    float y2 = fmaf(bflo(rawv.y), tsc[2], tsh[2]);
    float y3 = fmaf(bfhi(rawv.y), tsc[3], tsh[3]);
    y0 = y0 > 0.f ? y0 : 0.f; y1 = y1 > 0.f ? y1 : 0.f;
    y2 = y2 > 0.f ? y2 : 0.f; y3 = y3 > 0.f ? y3 : 0.f;
    *(uint2*)(&As[row * LDA2 + kk]) = make_uint2(packbf(y0, y1), packbf(y2, y3));
  }
  #pragma unroll
  for (int c = 0; c < 16; ++c) {
    int f = c * 256 + t;
    int k = f >> 6, n = f & 63;
    Bs[n * LDA2 + k] = f2bf(W[k * 128 + n0 + n]);
  }
  __syncthreads();
  int l = t & 63, wv = t >> 6;
  int lr = l & 15, q = l >> 4;
  int m0 = wv * 16;
  floatx4 acc[4];
  #pragma unroll
  for (int ni = 0; ni < 4; ++ni) acc[ni] = (floatx4)(0.f);
  #pragma unroll
  for (int ks = 0; ks < 64; ks += 32) {
    bf16x8 af = *(const bf16x8*)(&As[(m0 + lr) * LDA2 + ks + q * 8]);
    bf16x8 bfr[4];
    #pragma unroll
    for (int ni = 0; ni < 4; ++ni)
      bfr[ni] = *(const bf16x8*)(&Bs[(ni * 16 + lr) * LDA2 + ks + q * 8]);
    #pragma unroll
    for (int ni = 0; ni < 4; ++ni)
      acc[ni] = __builtin_amdgcn_mfma_f32_16x16x32_bf16(af, bfr[ni], acc[ni], 0, 0, 0);
  }
  __syncthreads();          // As reads done; reuse As as Tr[64][TRS]
  #pragma unroll
  for (int ni = 0; ni < 4; ++ni) {
    int lc = ni * 16 + lr;
    int col = n0 + lc;
    float bv = bias[col];
    float s = 0.f, s2 = 0.f;
    #pragma unroll
    for (int r = 0; r < 4; ++r) {
      float y = acc[ni][r] + bv;
      s += y; s2 += y * y;
      As[(m0 + q * 4 + r) * TRS + lc] = f2bf(y);
    }
    atomicAdd(&sred[lc], s);
    atomicAdd(&sred[64 + lc], s2);
  }
  __syncthreads();
  #pragma unroll
  for (int i = 0; i < 2; ++i) {
    int idx = i * 256 + t;              // 0..511: 64 rows x 8 chunks
    int rowIdx = idx >> 3, c0 = (idx & 7) * 8;
    uint4 d = *(const uint4*)(&As[rowIdx * TRS + c0]);
    *(uint4*)(Y + (size_t)(row0 + rowIdx) * 128 + n0 + c0) = d;
  }
  // gsumOut: [0..127]=sums, [128..255]=sumsq (128 channels)
  if (t < 128) {
    int lc = t & 63, p = t >> 6;
    atomicAdd(&gsumOut[p * 128 + n0 + lc], sred[t]);
  }
}

// ---------------- final BN apply + ReLU, bf16 -> fp32 ----------------------
__global__ __launch_bounds__(256) void bn_apply_final(const unsigned short* __restrict__ T,
    float* __restrict__ Y, const float* __restrict__ gsum,
    const float* __restrict__ gamma, const float* __restrict__ beta) {
  size_t i4 = ((size_t)blockIdx.x * 256 + threadIdx.x) * 4;
  int c0 = (int)(i4 & 127);
  ushort4 tv = *(const ushort4*)(T + i4);
  unsigned short sv[4] = {tv.x, tv.y, tv.z, tv.w};
  float ov[4];
  #pragma unroll
  for (int j = 0; j < 4; ++j) {
    int c = c0 + j;
    float sc, sh;
    scsh_from(gsum, gamma, beta, c, 128, sc, sh);
    float y = fmaf(bf2f(sv[j]), sc, sh);
    ov[j] = y > 0.f ? y : 0.f;
  }
  *(float4*)(Y + i4) = make_float4(ov[0], ov[1], ov[2], ov[3]);
}

extern "C" void kernel_launch(void* const* d_in, const int* in_sizes, int n_in,
                              void* d_out, int out_size, void* d_ws, size_t ws_size,
                              hipStream_t stream) {
  const float* x    = (const float*)d_in[0];
  const int*   cols = (const int*)  d_in[2];
  const float* vals = (const float*)d_in[3];
  const float* W1   = (const float*)d_in[4];
  const float* b1   = (const float*)d_in[5];
  const float* g1   = (const float*)d_in[6];
  const float* be1  = (const float*)d_in[7];
  const float* W2   = (const float*)d_in[8];
  const float* b2   = (const float*)d_in[9];
  const float* g2   = (const float*)d_in[10];
  const float* be2  = (const float*)d_in[11];
  const float* W3   = (const float*)d_in[12];
  const float* b3   = (const float*)d_in[13];
  const float* g3   = (const float*)d_in[14];
  const float* be3  = (const float*)d_in[15];
  float* out = (float*)d_out;

  const size_t PL = (size_t)MROWS * 64;          // plane elements
  unsigned short* P0 = (unsigned short*)d_ws;    // t1, then t2
  unsigned short* P1 = P0 + PL;                  // x1
  unsigned short* P2 = P1 + PL;                  // x2, then t3 [MROWS,128]
  float* ctrl  = (float*)(P2 + 2 * PL);
  float* gsum1 = ctrl;                           // 128 (64 sum + 64 sumsq)
  float* gsum2 = ctrl + 128;                     // 128
  float* gsum3 = ctrl + 256;                     // 256 (128 sum + 128 sumsq)

  // zero stat accumulators (ws is re-poisoned by the harness each iter)
  hipMemsetAsync(ctrl, 0, 512 * sizeof(float), stream);

  dim3 blk(256);
  int rowb = MROWS / 64;                         // 1536
  int spmm_blocks = 3072;                        // 64 rows x 4 combos
  int ap128_blocks = (int)(PL * 2 / 4 / 256);    // 12288

  // Layer 1
  gemm1<<<rowb, blk, 0, stream>>>(x, W1, b1, P0, gsum1);

  // Layer 2 (K=3 Chebyshev); h1 = relu(bn1(t1)) applied inline everywhere
  spmm1<<<spmm_blocks, blk, 0, stream>>>(P0, cols, vals, gsum1, g1, be1, P1);
  spmm2<<<spmm_blocks, blk, 0, stream>>>(P1, P0, cols, vals, gsum1, g1, be1, P2);
  gemm2<<<rowb, blk, 0, stream>>>(P0, P1, P2, W2, b2, gsum1, g1, be1, P0, gsum2);

  // Layer 3; bn2-apply fused into gemm3 A-staging; two 64-col halves
  dim3 g3grid(rowb, 2);
  gemm3<<<g3grid, blk, 0, stream>>>(P0, W3, b3, gsum2, g2, be2, P2, gsum3);
  bn_apply_final<<<ap128_blocks, blk, 0, stream>>>(P2, out, gsum3, g3, be3);
}

// Round 6
// 347.753 us; speedup vs baseline: 1.0316x; 1.0316x over previous
//
#include <hip/hip_runtime.h>

#define VN 49152
#define DEG 20
#define NB 2
#define MROWS (NB * VN)   // 98304 rows

static constexpr float BN_EPS = 1e-5f;

typedef short bf16x8 __attribute__((ext_vector_type(8)));
typedef float floatx4 __attribute__((ext_vector_type(4)));

__device__ __forceinline__ unsigned short f2bf(float f) {
  unsigned int u = __builtin_bit_cast(unsigned int, f);
  u += 0x7FFFu + ((u >> 16) & 1u);            // RNE
  return (unsigned short)(u >> 16);
}
__device__ __forceinline__ float bf2f(unsigned short h) {
  unsigned int u = ((unsigned int)h) << 16;
  return __builtin_bit_cast(float, u);
}
// packed-bf16 tricks: 1 VALU per element
__device__ __forceinline__ float bflo(unsigned int u) {
  return __builtin_bit_cast(float, u << 16);
}
__device__ __forceinline__ float bfhi(unsigned int u) {
  return __builtin_bit_cast(float, u & 0xFFFF0000u);
}
__device__ __forceinline__ unsigned int packbf(float a, float b) {
  return (unsigned int)f2bf(a) | ((unsigned int)f2bf(b) << 16);
}

// Per-channel BN scale/shift recomputed by CONSUMERS from gsum partials.
// gsum layout: [0..S-1] = channel sums, [S..2S-1] = channel sumsq.
__device__ __forceinline__ void scsh_from(const float* __restrict__ gsum,
    const float* __restrict__ gamma, const float* __restrict__ beta,
    int c, int S, float& sc, float& sh) {
  float mean = gsum[c] * (1.f / MROWS);
  float var  = gsum[S + c] * (1.f / MROWS) - mean * mean;
  sc = gamma[c] * rsqrtf(var + BN_EPS);
  sh = beta[c] - mean * sc;
}

// Feature planes (64-ch) are stored SWIZZLED as 4 sub-planes
// [batch][chalf][VN][32]: addr(b,v,ch) = ((b*2 + ch/32)*VN + v)*32 + ch%32.
//
// GEMMs use 128-row tiles (round-5 falsified the occupancy theory: M=64
// doubled per-block staging overhead and regressed 23%; M=128 is measured
// best). Epilogues transpose acc through LDS (TRS stride 72 shorts = 144 B,
// keeps 16 B alignment) so global stores are full-line coalesced.
// spmm2 is FUSED into gemm2: x2 rows are gathered in-kernel from the x1
// plane (identical arithmetic, minus one dispatch and an x2 round-trip).
#define TRS 72

// ======================= GEMM1: t1 = x @ W1 + b1 ===========================
#define LDA1 136
__global__ __launch_bounds__(256) void gemm1(const float* __restrict__ X,
    const float* __restrict__ W, const float* __restrict__ bias,
    unsigned short* __restrict__ Y, float* __restrict__ gsum) {
  __shared__ unsigned short As[128 * LDA1];
  __shared__ unsigned short Bs[64 * LDA1];
  __shared__ float sred[128];
  int t = threadIdx.x;
  int row0 = blockIdx.x * 128;
  if (t < 128) sred[t] = 0.f;
  const float* Xt = X + (size_t)row0 * 128;
  #pragma unroll
  for (int c = 0; c < 16; ++c) {
    int f4i = c * 256 + t;
    int row = f4i >> 5, k = (f4i & 31) * 4;
    float4 v = *(const float4*)(Xt + row * 128 + k);
    *(uint2*)(&As[row * LDA1 + k]) = make_uint2(packbf(v.x, v.y), packbf(v.z, v.w));
  }
  #pragma unroll
  for (int c = 0; c < 32; ++c) {
    int f = c * 256 + t;
    int k = f >> 6, n = f & 63;
    Bs[n * LDA1 + k] = f2bf(W[f]);
  }
  __syncthreads();
  int l = t & 63, wv = t >> 6;
  int lr = l & 15, q = l >> 4;
  int m0 = wv * 32;
  floatx4 acc[2][4];
  #pragma unroll
  for (int mi = 0; mi < 2; ++mi)
    #pragma unroll
    for (int ni = 0; ni < 4; ++ni) acc[mi][ni] = (floatx4)(0.f);
  #pragma unroll
  for (int ks = 0; ks < 128; ks += 32) {
    bf16x8 af[2], bfr[4];
    #pragma unroll
    for (int mi = 0; mi < 2; ++mi)
      af[mi] = *(const bf16x8*)(&As[(m0 + mi * 16 + lr) * LDA1 + ks + q * 8]);
    #pragma unroll
    for (int ni = 0; ni < 4; ++ni)
      bfr[ni] = *(const bf16x8*)(&Bs[(ni * 16 + lr) * LDA1 + ks + q * 8]);
    #pragma unroll
    for (int mi = 0; mi < 2; ++mi)
      #pragma unroll
      for (int ni = 0; ni < 4; ++ni)
        acc[mi][ni] = __builtin_amdgcn_mfma_f32_16x16x32_bf16(af[mi], bfr[ni], acc[mi][ni], 0, 0, 0);
  }
  __syncthreads();          // all As/Bs reads done; reuse As as Tr[128][TRS]
  int b = (row0 >= VN) ? 1 : 0;
  int b2 = b * 2, vb0 = row0 - b * VN;
  #pragma unroll
  for (int ni = 0; ni < 4; ++ni) {
    int col = ni * 16 + lr;
    float bv = bias[col];
    float s = 0.f, s2 = 0.f;
    #pragma unroll
    for (int mi = 0; mi < 2; ++mi)
      #pragma unroll
      for (int r = 0; r < 4; ++r) {
        float y = acc[mi][ni][r] + bv;
        s += y; s2 += y * y;
        As[(m0 + mi * 16 + q * 4 + r) * TRS + col] = f2bf(y);
      }
    atomicAdd(&sred[col], s);
    atomicAdd(&sred[64 + col], s2);
  }
  __syncthreads();
  #pragma unroll
  for (int i = 0; i < 4; ++i) {
    int idx = i * 256 + t;
    int p = idx >> 9, rem = idx & 511;
    int rowIdx = rem >> 2, ch0 = (rem & 3) * 8;
    uint4 d = *(const uint4*)(&As[rowIdx * TRS + p * 32 + ch0]);
    *(uint4*)(Y + ((size_t)(b2 + p) * VN + vb0 + rowIdx) * 32 + ch0) = d;
  }
  if (t < 128) atomicAdd(&gsum[t], sred[t]);
}

// ---------------- spmm1: x1 = L relu(bn1(t1))  (BN applied inline) ---------
__global__ __launch_bounds__(256) void spmm1(const unsigned short* __restrict__ T1,
    const int* __restrict__ cols, const float* __restrict__ vals,
    const float* __restrict__ gsum, const float* __restrict__ gamma,
    const float* __restrict__ beta, unsigned short* __restrict__ X1out) {
  int g = blockIdx.x;
  int combo = (g & 7) >> 1;
  int rg = ((g >> 3) << 1) | (g & 1);
  int t = threadIdx.x;
  int wv = t >> 6, lane = t & 63;
  int v = rg * 64 + wv * 16 + (lane >> 2);
  int ch0 = (lane & 3) * 8;
  int cb = (combo & 1) * 32 + ch0;
  float sc[8], sh[8];
  #pragma unroll
  for (int j = 0; j < 8; ++j) scsh_from(gsum, gamma, beta, cb + j, 64, sc[j], sh[j]);
  const unsigned short* __restrict__ plane = T1 + (size_t)combo * VN * 32;
  float a[8];
  {
    float w0 = vals[v];
    uint4 d = *(const uint4*)(plane + (size_t)v * 32 + ch0);
    float e[8] = {bflo(d.x), bfhi(d.x), bflo(d.y), bfhi(d.y),
                  bflo(d.z), bfhi(d.z), bflo(d.w), bfhi(d.w)};
    #pragma unroll
    for (int j = 0; j < 8; ++j) {
      float h = fmaf(e[j], sc[j], sh[j]);
      h = h > 0.f ? h : 0.f;
      a[j] = w0 * h;
    }
  }
  const int*   __restrict__ cp = cols + VN + v * DEG;
  const float* __restrict__ vp = vals + VN + v * DEG;
  #pragma unroll
  for (int j = 0; j < DEG; ++j) {
    int cj = cp[j];
    float wj = vp[j];
    uint4 d = *(const uint4*)(plane + (size_t)cj * 32 + ch0);
    float e[8] = {bflo(d.x), bfhi(d.x), bflo(d.y), bfhi(d.y),
                  bflo(d.z), bfhi(d.z), bflo(d.w), bfhi(d.w)};
    #pragma unroll
    for (int i = 0; i < 8; ++i) {
      float h = fmaf(e[i], sc[i], sh[i]);
      h = h > 0.f ? h : 0.f;
      a[i] = fmaf(h, wj, a[i]);
    }
  }
  uint4 o;
  o.x = packbf(a[0], a[1]); o.y = packbf(a[2], a[3]);
  o.z = packbf(a[4], a[5]); o.w = packbf(a[6], a[7]);
  *(uint4*)(X1out + (size_t)combo * VN * 32 + (size_t)v * 32 + ch0) = o;
}

// ===== GEMM2 (+fused spmm2): t2 = h1@W2[0] + x1@W2[1] + x2@W2[2] + b2 ======
// x2 = 2*(L x1) - h1 is computed IN-KERNEL for the block's own 128 rows by
// gathering x1 neighbors (this is spmm2's exact arithmetic, relocated).
// h1 = relu(bn1(t1)) applied inline; sc/sh cached in LDS (scsh_s).
// Y aliases X0 (t2 overwrites t1): safe — t1 reads (terms 0,2) precede the
// epilogue write, and each block touches only its own rows.
#define LDA2 72
__global__ __launch_bounds__(256) void gemm2(const unsigned short* X0,
    const unsigned short* __restrict__ X1,
    const int* __restrict__ colsG, const float* __restrict__ valsG,
    const float* __restrict__ W, const float* __restrict__ bias,
    const float* __restrict__ gsumIn, const float* __restrict__ gamma,
    const float* __restrict__ beta, unsigned short* Y,
    float* __restrict__ gsumOut) {
  __shared__ unsigned short As[128 * LDA2];
  __shared__ unsigned short Bs[64 * LDA2];
  __shared__ float sred[128];
  __shared__ float scsh_s[128];   // [0..63]=sc, [64..127]=sh for bn1
  int t = threadIdx.x;
  int row0 = blockIdx.x * 128;
  int b = (row0 >= VN) ? 1 : 0;
  int b2 = b * 2;
  int vb0 = row0 - b * VN;
  if (t < 128) sred[t] = 0.f;
  if (t >= 128 && t < 192) {
    int c = t - 128;
    float sc, sh;
    scsh_from(gsumIn, gamma, beta, c, 64, sc, sh);
    scsh_s[c] = sc; scsh_s[64 + c] = sh;
  }
  __syncthreads();

  int kk = (t & 15) * 4;    // staging: 16 threads/row-group, k invariant
  int r0 = t >> 4;
  int l = t & 63, wv = t >> 6;
  int lr = l & 15, q = l >> 4;
  int m0 = wv * 32;
  floatx4 acc[2][4];
  #pragma unroll
  for (int mi = 0; mi < 2; ++mi)
    #pragma unroll
    for (int ni = 0; ni < 4; ++ni) acc[mi][ni] = (floatx4)(0.f);

  // ---------------- term 0: A = h1 = relu(bn1(t1)) -------------------------
  {
    float tsc[4], tsh[4];
    #pragma unroll
    for (int j = 0; j < 4; ++j) { tsc[j] = scsh_s[kk + j]; tsh[j] = scsh_s[64 + kk + j]; }
    const unsigned short* srcBase =
        X0 + ((size_t)(b2 + (kk >> 5)) * VN + vb0) * 32 + (kk & 31);
    #pragma unroll
    for (int c8 = 0; c8 < 8; ++c8) {
      int row = c8 * 16 + r0;
      uint2 rawv = *(const uint2*)(srcBase + (size_t)row * 32);
      float y0 = fmaf(bflo(rawv.x), tsc[0], tsh[0]);
      float y1 = fmaf(bfhi(rawv.x), tsc[1], tsh[1]);
      float y2 = fmaf(bflo(rawv.y), tsc[2], tsh[2]);
      float y3 = fmaf(bfhi(rawv.y), tsc[3], tsh[3]);
      y0 = y0 > 0.f ? y0 : 0.f; y1 = y1 > 0.f ? y1 : 0.f;
      y2 = y2 > 0.f ? y2 : 0.f; y3 = y3 > 0.f ? y3 : 0.f;
      *(uint2*)(&As[row * LDA2 + kk]) = make_uint2(packbf(y0, y1), packbf(y2, y3));
    }
    #pragma unroll
    for (int c = 0; c < 16; ++c) {
      int f = c * 256 + t;
      int k = f >> 6, n = f & 63;
      Bs[n * LDA2 + k] = f2bf(W[f]);
    }
    __syncthreads();
    #pragma unroll
    for (int ks = 0; ks < 64; ks += 32) {
      bf16x8 af[2], bfr[4];
      #pragma unroll
      for (int mi = 0; mi < 2; ++mi)
        af[mi] = *(const bf16x8*)(&As[(m0 + mi * 16 + lr) * LDA2 + ks + q * 8]);
      #pragma unroll
      for (int ni = 0; ni < 4; ++ni)
        bfr[ni] = *(const bf16x8*)(&Bs[(ni * 16 + lr) * LDA2 + ks + q * 8]);
      #pragma unroll
      for (int mi = 0; mi < 2; ++mi)
        #pragma unroll
        for (int ni = 0; ni < 4; ++ni)
          acc[mi][ni] = __builtin_amdgcn_mfma_f32_16x16x32_bf16(af[mi], bfr[ni], acc[mi][ni], 0, 0, 0);
    }
    __syncthreads();
  }

  // ---------------- term 1: A = x1 (direct copy) ---------------------------
  {
    const unsigned short* srcBase =
        X1 + ((size_t)(b2 + (kk >> 5)) * VN + vb0) * 32 + (kk & 31);
    #pragma unroll
    for (int c8 = 0; c8 < 8; ++c8) {
      int row = c8 * 16 + r0;
      *(uint2*)(&As[row * LDA2 + kk]) = *(const uint2*)(srcBase + (size_t)row * 32);
    }
    #pragma unroll
    for (int c = 0; c < 16; ++c) {
      int f = c * 256 + t;
      int k = f >> 6, n = f & 63;
      Bs[n * LDA2 + k] = f2bf(W[64 * 64 + f]);
    }
    __syncthreads();
    #pragma unroll
    for (int ks = 0; ks < 64; ks += 32) {
      bf16x8 af[2], bfr[4];
      #pragma unroll
      for (int mi = 0; mi < 2; ++mi)
        af[mi] = *(const bf16x8*)(&As[(m0 + mi * 16 + lr) * LDA2 + ks + q * 8]);
      #pragma unroll
      for (int ni = 0; ni < 4; ++ni)
        bfr[ni] = *(const bf16x8*)(&Bs[(ni * 16 + lr) * LDA2 + ks + q * 8]);
      #pragma unroll
      for (int mi = 0; mi < 2; ++mi)
        #pragma unroll
        for (int ni = 0; ni < 4; ++ni)
          acc[mi][ni] = __builtin_amdgcn_mfma_f32_16x16x32_bf16(af[mi], bfr[ni], acc[mi][ni], 0, 0, 0);
    }
    __syncthreads();
  }

  // -------- term 2: A = x2 = 2*(L x1) - h1  (fused spmm2 gather) -----------
  {
    // thread -> (row = t>>1, half = t&1): one 32-ch sub-plane slice per thread
    int row = t >> 1;
    int half = t & 1;
    int v = vb0 + row;
    const unsigned short* plane = X1 + (size_t)(b2 + half) * VN * 32;
    float a[4][8];
    {
      float w0 = valsG[v];
      #pragma unroll
      for (int g = 0; g < 4; ++g) {
        uint4 d = *(const uint4*)(plane + (size_t)v * 32 + g * 8);
        a[g][0] = w0 * bflo(d.x); a[g][1] = w0 * bfhi(d.x);
        a[g][2] = w0 * bflo(d.y); a[g][3] = w0 * bfhi(d.y);
        a[g][4] = w0 * bflo(d.z); a[g][5] = w0 * bfhi(d.z);
        a[g][6] = w0 * bflo(d.w); a[g][7] = w0 * bfhi(d.w);
      }
    }
    const int*   cp = colsG + VN + v * DEG;
    const float* vp = valsG + VN + v * DEG;
    #pragma unroll
    for (int j = 0; j < DEG; ++j) {
      int cj = cp[j];
      float wj = vp[j];
      const unsigned short* src = plane + (size_t)cj * 32;
      #pragma unroll
      for (int g = 0; g < 4; ++g) {
        uint4 d = *(const uint4*)(src + g * 8);
        a[g][0] = fmaf(bflo(d.x), wj, a[g][0]); a[g][1] = fmaf(bfhi(d.x), wj, a[g][1]);
        a[g][2] = fmaf(bflo(d.y), wj, a[g][2]); a[g][3] = fmaf(bfhi(d.y), wj, a[g][3]);
        a[g][4] = fmaf(bflo(d.z), wj, a[g][4]); a[g][5] = fmaf(bfhi(d.z), wj, a[g][5]);
        a[g][6] = fmaf(bflo(d.w), wj, a[g][6]); a[g][7] = fmaf(bfhi(d.w), wj, a[g][7]);
      }
    }
    const unsigned short* trow = X0 + ((size_t)(b2 + half) * VN + v) * 32;
    #pragma unroll
    for (int g = 0; g < 4; ++g) {
      uint4 hr = *(const uint4*)(trow + g * 8);
      int cb = half * 32 + g * 8;
      float e[8] = {bflo(hr.x), bfhi(hr.x), bflo(hr.y), bfhi(hr.y),
                    bflo(hr.z), bfhi(hr.z), bflo(hr.w), bfhi(hr.w)};
      float oo[8];
      #pragma unroll
      for (int k = 0; k < 8; ++k) {
        float h = fmaf(e[k], scsh_s[cb + k], scsh_s[64 + cb + k]);
        h = h > 0.f ? h : 0.f;
        oo[k] = 2.f * a[g][k] - h;
      }
      uint4 o;
      o.x = packbf(oo[0], oo[1]); o.y = packbf(oo[2], oo[3]);
      o.z = packbf(oo[4], oo[5]); o.w = packbf(oo[6], oo[7]);
      *(uint4*)(&As[row * LDA2 + cb]) = o;
    }
    #pragma unroll
    for (int c = 0; c < 16; ++c) {
      int f = c * 256 + t;
      int k = f >> 6, n = f & 63;
      Bs[n * LDA2 + k] = f2bf(W[2 * 64 * 64 + f]);
    }
    __syncthreads();
    #pragma unroll
    for (int ks = 0; ks < 64; ks += 32) {
      bf16x8 af[2], bfr[4];
      #pragma unroll
      for (int mi = 0; mi < 2; ++mi)
        af[mi] = *(const bf16x8*)(&As[(m0 + mi * 16 + lr) * LDA2 + ks + q * 8]);
      #pragma unroll
      for (int ni = 0; ni < 4; ++ni)
        bfr[ni] = *(const bf16x8*)(&Bs[(ni * 16 + lr) * LDA2 + ks + q * 8]);
      #pragma unroll
      for (int mi = 0; mi < 2; ++mi)
        #pragma unroll
        for (int ni = 0; ni < 4; ++ni)
          acc[mi][ni] = __builtin_amdgcn_mfma_f32_16x16x32_bf16(af[mi], bfr[ni], acc[mi][ni], 0, 0, 0);
    }
    __syncthreads();
  }

  // epilogue: transpose through As (reuse, Tr[128][TRS]) -> coalesced stores
  #pragma unroll
  for (int ni = 0; ni < 4; ++ni) {
    int col = ni * 16 + lr;
    float bv = bias[col];
    float s = 0.f, s2 = 0.f;
    #pragma unroll
    for (int mi = 0; mi < 2; ++mi)
      #pragma unroll
      for (int r = 0; r < 4; ++r) {
        float y = acc[mi][ni][r] + bv;
        s += y; s2 += y * y;
        As[(m0 + mi * 16 + q * 4 + r) * TRS + col] = f2bf(y);
      }
    atomicAdd(&sred[col], s);
    atomicAdd(&sred[64 + col], s2);
  }
  __syncthreads();
  #pragma unroll
  for (int i = 0; i < 4; ++i) {
    int idx = i * 256 + t;
    int p = idx >> 9, rem = idx & 511;
    int rowIdx = rem >> 2, ch0 = (rem & 3) * 8;
    uint4 d = *(const uint4*)(&As[rowIdx * TRS + p * 32 + ch0]);
    *(uint4*)(Y + ((size_t)(b2 + p) * VN + vb0 + rowIdx) * 32 + ch0) = d;
  }
  if (t < 128) atomicAdd(&gsumOut[t], sred[t]);
}

// ====== GEMM3: t3 = relu(bn2(t2)) @ W3 + b3  (two 64-col halves, y-grid) ===
__global__ __launch_bounds__(256) void gemm3(const unsigned short* __restrict__ X,
    const float* __restrict__ W, const float* __restrict__ bias,
    const float* __restrict__ gsumIn, const float* __restrict__ gamma,
    const float* __restrict__ beta, unsigned short* __restrict__ Y,
    float* __restrict__ gsumOut) {
  __shared__ unsigned short As[128 * LDA2];
  __shared__ unsigned short Bs[64 * LDA2];
  __shared__ float sred[128];
  int t = threadIdx.x;
  int row0 = blockIdx.x * 128;
  int n0 = blockIdx.y * 64;
  int b = (row0 >= VN) ? 1 : 0;
  int b2 = b * 2;
  int vb0 = row0 - b * VN;
  if (t < 128) sred[t] = 0.f;
  int kk = (t & 15) * 4;
  int r0 = t >> 4;
  float tsc[4], tsh[4];
  #pragma unroll
  for (int j = 0; j < 4; ++j) scsh_from(gsumIn, gamma, beta, kk + j, 64, tsc[j], tsh[j]);
  const unsigned short* srcBase =
      X + ((size_t)(b2 + (kk >> 5)) * VN + vb0) * 32 + (kk & 31);
  #pragma unroll
  for (int c8 = 0; c8 < 8; ++c8) {
    int row = c8 * 16 + r0;
    uint2 rawv = *(const uint2*)(srcBase + (size_t)row * 32);
    float y0 = fmaf(bflo(rawv.x), tsc[0], tsh[0]);
    float y1 = fmaf(bfhi(rawv.x), tsc[1], tsh[1]);
    float y2 = fmaf(bflo(rawv.y), tsc[2], tsh[2]);
    float y3 = fmaf(bfhi(rawv.y), tsc[3], tsh[3]);
    y0 = y0 > 0.f ? y0 : 0.f; y1 = y1 > 0.f ? y1 : 0.f;
    y2 = y2 > 0.f ? y2 : 0.f; y3 = y3 > 0.f ? y3 : 0.f;
    *(uint2*)(&As[row * LDA2 + kk]) = make_uint2(packbf(y0, y1), packbf(y2, y3));
  }
  #pragma unroll
  for (int c = 0; c < 16; ++c) {
    int f = c * 256 + t;
    int k = f >> 6, n = f & 63;
    Bs[n * LDA2 + k] = f2bf(W[k * 128 + n0 + n]);
  }
  __syncthreads();
  int l = t & 63, wv = t >> 6;
  int lr = l & 15, q = l >> 4;
  int m0 = wv * 32;
  floatx4 acc[2][4];
  #pragma unroll
  for (int mi = 0; mi < 2; ++mi)
    #pragma unroll
    for (int ni = 0; ni < 4; ++ni) acc[mi][ni] = (floatx4)(0.f);
  #pragma unroll
  for (int ks = 0; ks < 64; ks += 32) {
    bf16x8 af[2], bfr[4];
    #pragma unroll
    for (int mi = 0; mi < 2; ++mi)
      af[mi] = *(const bf16x8*)(&As[(m0 + mi * 16 + lr) * LDA2 + ks + q * 8]);
    #pragma unroll
    for (int ni = 0; ni < 4; ++ni)
      bfr[ni] = *(const bf16x8*)(&Bs[(ni * 16 + lr) * LDA2 + ks + q * 8]);
    #pragma unroll
    for (int mi = 0; mi < 2; ++mi)
      #pragma unroll
      for (int ni = 0; ni < 4; ++ni)
        acc[mi][ni] = __builtin_amdgcn_mfma_f32_16x16x32_bf16(af[mi], bfr[ni], acc[mi][ni], 0, 0, 0);
  }
  __syncthreads();          // As reads done; reuse As as Tr[128][TRS]
  #pragma unroll
  for (int ni = 0; ni < 4; ++ni) {
    int lc = ni * 16 + lr;
    int col = n0 + lc;
    float bv = bias[col];
    float s = 0.f, s2 = 0.f;
    #pragma unroll
    for (int mi = 0; mi < 2; ++mi)
      #pragma unroll
      for (int r = 0; r < 4; ++r) {
        float y = acc[mi][ni][r] + bv;
        s += y; s2 += y * y;
        As[(m0 + mi * 16 + q * 4 + r) * TRS + lc] = f2bf(y);
      }
    atomicAdd(&sred[lc], s);
    atomicAdd(&sred[64 + lc], s2);
  }
  __syncthreads();
  #pragma unroll
  for (int i = 0; i < 4; ++i) {
    int idx = i * 256 + t;
    int rowIdx = idx >> 3, c0 = (idx & 7) * 8;
    uint4 d = *(const uint4*)(&As[rowIdx * TRS + c0]);
    *(uint4*)(Y + (size_t)(row0 + rowIdx) * 128 + n0 + c0) = d;
  }
  // gsumOut: [0..127]=sums, [128..255]=sumsq (128 channels)
  if (t < 128) {
    int lc = t & 63, p = t >> 6;
    atomicAdd(&gsumOut[p * 128 + n0 + lc], sred[t]);
  }
}

// ---------------- final BN apply + ReLU, bf16 -> fp32 ----------------------
__global__ __launch_bounds__(256) void bn_apply_final(const unsigned short* __restrict__ T,
    float* __restrict__ Y, const float* __restrict__ gsum,
    const float* __restrict__ gamma, const float* __restrict__ beta) {
  size_t i4 = ((size_t)blockIdx.x * 256 + threadIdx.x) * 4;
  int c0 = (int)(i4 & 127);
  ushort4 tv = *(const ushort4*)(T + i4);
  unsigned short sv[4] = {tv.x, tv.y, tv.z, tv.w};
  float ov[4];
  #pragma unroll
  for (int j = 0; j < 4; ++j) {
    int c = c0 + j;
    float sc, sh;
    scsh_from(gsum, gamma, beta, c, 128, sc, sh);
    float y = fmaf(bf2f(sv[j]), sc, sh);
    ov[j] = y > 0.f ? y : 0.f;
  }
  *(float4*)(Y + i4) = make_float4(ov[0], ov[1], ov[2], ov[3]);
}

extern "C" void kernel_launch(void* const* d_in, const int* in_sizes, int n_in,
                              void* d_out, int out_size, void* d_ws, size_t ws_size,
                              hipStream_t stream) {
  const float* x    = (const float*)d_in[0];
  const int*   cols = (const int*)  d_in[2];
  const float* vals = (const float*)d_in[3];
  const float* W1   = (const float*)d_in[4];
  const float* b1   = (const float*)d_in[5];
  const float* g1   = (const float*)d_in[6];
  const float* be1  = (const float*)d_in[7];
  const float* W2   = (const float*)d_in[8];
  const float* b2   = (const float*)d_in[9];
  const float* g2   = (const float*)d_in[10];
  const float* be2  = (const float*)d_in[11];
  const float* W3   = (const float*)d_in[12];
  const float* b3   = (const float*)d_in[13];
  const float* g3   = (const float*)d_in[14];
  const float* be3  = (const float*)d_in[15];
  float* out = (float*)d_out;

  const size_t PL = (size_t)MROWS * 64;          // plane elements
  unsigned short* P0 = (unsigned short*)d_ws;    // t1, then t2
  unsigned short* P1 = P0 + PL;                  // x1
  unsigned short* P2 = P1 + PL;                  // t3 [MROWS,128]
  float* ctrl  = (float*)(P2 + 2 * PL);
  float* gsum1 = ctrl;                           // 128 (64 sum + 64 sumsq)
  float* gsum2 = ctrl + 128;                     // 128
  float* gsum3 = ctrl + 256;                     // 256 (128 sum + 128 sumsq)

  // zero stat accumulators (ws is re-poisoned by the harness each iter)
  hipMemsetAsync(ctrl, 0, 512 * sizeof(float), stream);

  dim3 blk(256);
  int rowb = MROWS / 128;                        // 768
  int spmm_blocks = 3072;                        // 64 rows x 4 combos
  int ap128_blocks = (int)(PL * 2 / 4 / 256);    // 12288

  // Layer 1
  gemm1<<<rowb, blk, 0, stream>>>(x, W1, b1, P0, gsum1);

  // Layer 2 (K=3 Chebyshev); h1 inline; spmm2 fused into gemm2
  spmm1<<<spmm_blocks, blk, 0, stream>>>(P0, cols, vals, gsum1, g1, be1, P1);
  gemm2<<<rowb, blk, 0, stream>>>(P0, P1, cols, vals, W2, b2, gsum1, g1, be1, P0, gsum2);

  // Layer 3; bn2-apply fused into gemm3 A-staging; two 64-col halves
  dim3 g3grid(rowb, 2);
  gemm3<<<g3grid, blk, 0, stream>>>(P0, W3, b3, gsum2, g2, be2, P2, gsum3);
  bn_apply_final<<<ap128_blocks, blk, 0, stream>>>(P2, out, gsum3, g3, be3);
}

// Round 7
// 259.208 us; speedup vs baseline: 1.3840x; 1.3416x over previous
//
#include <hip/hip_runtime.h>

#define VN 49152
#define DEG 20
#define NB 2
#define MROWS (NB * VN)   // 98304 rows

static constexpr float BN_EPS = 1e-5f;

typedef short bf16x8 __attribute__((ext_vector_type(8)));
typedef float floatx4 __attribute__((ext_vector_type(4)));

__device__ __forceinline__ unsigned short f2bf(float f) {
  unsigned int u = __builtin_bit_cast(unsigned int, f);
  u += 0x7FFFu + ((u >> 16) & 1u);            // RNE
  return (unsigned short)(u >> 16);
}
__device__ __forceinline__ float bf2f(unsigned short h) {
  unsigned int u = ((unsigned int)h) << 16;
  return __builtin_bit_cast(float, u);
}
// packed-bf16 tricks: 1 VALU per element
__device__ __forceinline__ float bflo(unsigned int u) {
  return __builtin_bit_cast(float, u << 16);
}
__device__ __forceinline__ float bfhi(unsigned int u) {
  return __builtin_bit_cast(float, u & 0xFFFF0000u);
}
__device__ __forceinline__ unsigned int packbf(float a, float b) {
  return (unsigned int)f2bf(a) | ((unsigned int)f2bf(b) << 16);
}

// BN stats: producers atomicAdd per-block partials into gsum REPLICA
// blockIdx&7 (8 replicas) -> 8x less per-line atomic contention; the
// end-of-kernel fence drains the atomic tail 8x faster. Consumers sum the
// 8 replicas once per block into an LDS scsh cache.
// Replica layout: g[rep*RS + c] = sum, g[rep*RS + S + c] = sumsq.
__device__ __forceinline__ void scsh_from8(const float* __restrict__ g,
    int RS, int c, int S, const float* __restrict__ gamma,
    const float* __restrict__ beta, float& sc, float& sh) {
  float s = 0.f, s2 = 0.f;
  #pragma unroll
  for (int r = 0; r < 8; ++r) { s += g[r * RS + c]; s2 += g[r * RS + S + c]; }
  float mean = s * (1.f / MROWS);
  float var  = s2 * (1.f / MROWS) - mean * mean;
  sc = gamma[c] * rsqrtf(var + BN_EPS);
  sh = beta[c] - mean * sc;
}

// Feature planes (64-ch) are stored SWIZZLED as 4 sub-planes
// [batch][chalf][VN][32]: addr(b,v,ch) = ((b*2 + ch/32)*VN + v)*32 + ch%32.
// A (batch,chalf) combo = contiguous 3.15 MB; spmm blocks pin combo via
// blockIdx%8 so each combo stays L2-resident on 2 XCDs (round-6 lesson:
// moving the gather into non-pinned kernels -> 311 MB HBM fetch, 2.5x slower).
//
// GEMMs: 128-row tiles (M=64 retile falsified in round 5, -23%); epilogues
// transpose acc through LDS (TRS stride 72 shorts = 144 B) for 16 B
// coalesced full-line stores (round-3: WRITE_SIZE 41->25 MB ideal).
#define TRS 72

// ======================= GEMM1: t1 = x @ W1 + b1 ===========================
#define LDA1 136
__global__ __launch_bounds__(256) void gemm1(const float* __restrict__ X,
    const float* __restrict__ W, const float* __restrict__ bias,
    unsigned short* __restrict__ Y, float* __restrict__ gsum) {
  __shared__ unsigned short As[128 * LDA1];
  __shared__ unsigned short Bs[64 * LDA1];
  __shared__ float sred[128];
  int t = threadIdx.x;
  int row0 = blockIdx.x * 128;
  if (t < 128) sred[t] = 0.f;
  const float* Xt = X + (size_t)row0 * 128;
  #pragma unroll
  for (int c = 0; c < 16; ++c) {
    int f4i = c * 256 + t;
    int row = f4i >> 5, k = (f4i & 31) * 4;
    float4 v = *(const float4*)(Xt + row * 128 + k);
    *(uint2*)(&As[row * LDA1 + k]) = make_uint2(packbf(v.x, v.y), packbf(v.z, v.w));
  }
  #pragma unroll
  for (int c = 0; c < 32; ++c) {
    int f = c * 256 + t;
    int k = f >> 6, n = f & 63;
    Bs[n * LDA1 + k] = f2bf(W[f]);
  }
  __syncthreads();
  int l = t & 63, wv = t >> 6;
  int lr = l & 15, q = l >> 4;
  int m0 = wv * 32;
  floatx4 acc[2][4];
  #pragma unroll
  for (int mi = 0; mi < 2; ++mi)
    #pragma unroll
    for (int ni = 0; ni < 4; ++ni) acc[mi][ni] = (floatx4)(0.f);
  #pragma unroll
  for (int ks = 0; ks < 128; ks += 32) {
    bf16x8 af[2], bfr[4];
    #pragma unroll
    for (int mi = 0; mi < 2; ++mi)
      af[mi] = *(const bf16x8*)(&As[(m0 + mi * 16 + lr) * LDA1 + ks + q * 8]);
    #pragma unroll
    for (int ni = 0; ni < 4; ++ni)
      bfr[ni] = *(const bf16x8*)(&Bs[(ni * 16 + lr) * LDA1 + ks + q * 8]);
    #pragma unroll
    for (int mi = 0; mi < 2; ++mi)
      #pragma unroll
      for (int ni = 0; ni < 4; ++ni)
        acc[mi][ni] = __builtin_amdgcn_mfma_f32_16x16x32_bf16(af[mi], bfr[ni], acc[mi][ni], 0, 0, 0);
  }
  __syncthreads();          // all As/Bs reads done; reuse As as Tr[128][TRS]
  int b = (row0 >= VN) ? 1 : 0;
  int b2 = b * 2, vb0 = row0 - b * VN;
  #pragma unroll
  for (int ni = 0; ni < 4; ++ni) {
    int col = ni * 16 + lr;
    float bv = bias[col];
    float s = 0.f, s2 = 0.f;
    #pragma unroll
    for (int mi = 0; mi < 2; ++mi)
      #pragma unroll
      for (int r = 0; r < 4; ++r) {
        float y = acc[mi][ni][r] + bv;
        s += y; s2 += y * y;
        As[(m0 + mi * 16 + q * 4 + r) * TRS + col] = f2bf(y);
      }
    atomicAdd(&sred[col], s);
    atomicAdd(&sred[64 + col], s2);
  }
  __syncthreads();
  #pragma unroll
  for (int i = 0; i < 4; ++i) {
    int idx = i * 256 + t;
    int p = idx >> 9, rem = idx & 511;
    int rowIdx = rem >> 2, ch0 = (rem & 3) * 8;
    uint4 d = *(const uint4*)(&As[rowIdx * TRS + p * 32 + ch0]);
    *(uint4*)(Y + ((size_t)(b2 + p) * VN + vb0 + rowIdx) * 32 + ch0) = d;
  }
  if (t < 128) atomicAdd(&gsum[(blockIdx.x & 7) * 128 + t], sred[t]);
}

// ---------------- spmm1: x1 = L relu(bn1(t1))  (BN applied inline) ---------
__global__ __launch_bounds__(256) void spmm1(const unsigned short* __restrict__ T1,
    const int* __restrict__ cols, const float* __restrict__ vals,
    const float* __restrict__ gsum, const float* __restrict__ gamma,
    const float* __restrict__ beta, unsigned short* __restrict__ X1out) {
  __shared__ float scsh_s[64];     // [0..31]=sc, [32..63]=sh for block's 32 ch
  int g = blockIdx.x;
  int combo = (g & 7) >> 1;
  int rg = ((g >> 3) << 1) | (g & 1);
  int t = threadIdx.x;
  int cwin0 = (combo & 1) * 32;
  if (t < 32) {
    float sc, sh;
    scsh_from8(gsum, 128, cwin0 + t, 64, gamma, beta, sc, sh);
    scsh_s[t] = sc; scsh_s[32 + t] = sh;
  }
  __syncthreads();
  int wv = t >> 6, lane = t & 63;
  int v = rg * 64 + wv * 16 + (lane >> 2);
  int ch0 = (lane & 3) * 8;
  float sc[8], sh[8];
  #pragma unroll
  for (int j = 0; j < 8; ++j) { sc[j] = scsh_s[ch0 + j]; sh[j] = scsh_s[32 + ch0 + j]; }
  const unsigned short* __restrict__ plane = T1 + (size_t)combo * VN * 32;
  float a[8];
  {
    float w0 = vals[v];
    uint4 d = *(const uint4*)(plane + (size_t)v * 32 + ch0);
    float e[8] = {bflo(d.x), bfhi(d.x), bflo(d.y), bfhi(d.y),
                  bflo(d.z), bfhi(d.z), bflo(d.w), bfhi(d.w)};
    #pragma unroll
    for (int j = 0; j < 8; ++j) {
      float h = fmaf(e[j], sc[j], sh[j]);
      h = h > 0.f ? h : 0.f;
      a[j] = w0 * h;
    }
  }
  const int*   __restrict__ cp = cols + VN + v * DEG;
  const float* __restrict__ vp = vals + VN + v * DEG;
  #pragma unroll
  for (int j = 0; j < DEG; ++j) {
    int cj = cp[j];
    float wj = vp[j];
    uint4 d = *(const uint4*)(plane + (size_t)cj * 32 + ch0);
    float e[8] = {bflo(d.x), bfhi(d.x), bflo(d.y), bfhi(d.y),
                  bflo(d.z), bfhi(d.z), bflo(d.w), bfhi(d.w)};
    #pragma unroll
    for (int i = 0; i < 8; ++i) {
      float h = fmaf(e[i], sc[i], sh[i]);
      h = h > 0.f ? h : 0.f;
      a[i] = fmaf(h, wj, a[i]);
    }
  }
  uint4 o;
  o.x = packbf(a[0], a[1]); o.y = packbf(a[2], a[3]);
  o.z = packbf(a[4], a[5]); o.w = packbf(a[6], a[7]);
  *(uint4*)(X1out + (size_t)combo * VN * 32 + (size_t)v * 32 + ch0) = o;
}

// ------------- spmm2: x2 = 2*(L x1) - relu(bn1(t1)) ------------------------
__global__ __launch_bounds__(256) void spmm2(const unsigned short* __restrict__ X1,
    const unsigned short* __restrict__ T1, const int* __restrict__ cols,
    const float* __restrict__ vals, const float* __restrict__ gsum,
    const float* __restrict__ gamma, const float* __restrict__ beta,
    unsigned short* __restrict__ X2out) {
  __shared__ float scsh_s[64];
  int g = blockIdx.x;
  int combo = (g & 7) >> 1;
  int rg = ((g >> 3) << 1) | (g & 1);
  int t = threadIdx.x;
  int cwin0 = (combo & 1) * 32;
  if (t < 32) {
    float sc, sh;
    scsh_from8(gsum, 128, cwin0 + t, 64, gamma, beta, sc, sh);
    scsh_s[t] = sc; scsh_s[32 + t] = sh;
  }
  __syncthreads();
  int wv = t >> 6, lane = t & 63;
  int v = rg * 64 + wv * 16 + (lane >> 2);
  int ch0 = (lane & 3) * 8;
  const size_t pbase = (size_t)combo * VN * 32;
  const size_t myoff = pbase + (size_t)v * 32 + ch0;
  const unsigned short* __restrict__ plane = X1 + pbase;
  float a[8];
  {
    float w0 = vals[v];
    uint4 d = *(const uint4*)(X1 + myoff);
    a[0] = w0 * bflo(d.x); a[1] = w0 * bfhi(d.x);
    a[2] = w0 * bflo(d.y); a[3] = w0 * bfhi(d.y);
    a[4] = w0 * bflo(d.z); a[5] = w0 * bfhi(d.z);
    a[6] = w0 * bflo(d.w); a[7] = w0 * bfhi(d.w);
  }
  const int*   __restrict__ cp = cols + VN + v * DEG;
  const float* __restrict__ vp = vals + VN + v * DEG;
  #pragma unroll
  for (int j = 0; j < DEG; ++j) {
    int cj = cp[j];
    float wj = vp[j];
    uint4 d = *(const uint4*)(plane + (size_t)cj * 32 + ch0);
    a[0] = fmaf(bflo(d.x), wj, a[0]); a[1] = fmaf(bfhi(d.x), wj, a[1]);
    a[2] = fmaf(bflo(d.y), wj, a[2]); a[3] = fmaf(bfhi(d.y), wj, a[3]);
    a[4] = fmaf(bflo(d.z), wj, a[4]); a[5] = fmaf(bfhi(d.z), wj, a[5]);
    a[6] = fmaf(bflo(d.w), wj, a[6]); a[7] = fmaf(bfhi(d.w), wj, a[7]);
  }
  float sc[8], sh[8];
  #pragma unroll
  for (int j = 0; j < 8; ++j) { sc[j] = scsh_s[ch0 + j]; sh[j] = scsh_s[32 + ch0 + j]; }
  uint4 hr = *(const uint4*)(T1 + myoff);
  float e[8] = {bflo(hr.x), bfhi(hr.x), bflo(hr.y), bfhi(hr.y),
                bflo(hr.z), bfhi(hr.z), bflo(hr.w), bfhi(hr.w)};
  float oo[8];
  #pragma unroll
  for (int j = 0; j < 8; ++j) {
    float h = fmaf(e[j], sc[j], sh[j]);
    h = h > 0.f ? h : 0.f;
    oo[j] = 2.f * a[j] - h;
  }
  uint4 o;
  o.x = packbf(oo[0], oo[1]); o.y = packbf(oo[2], oo[3]);
  o.z = packbf(oo[4], oo[5]); o.w = packbf(oo[6], oo[7]);
  *(uint4*)(X2out + myoff) = o;
}

// ===== GEMM2: t2 = h1@W2[0] + x1@W2[1] + x2@W2[2] + b2 =====================
// h1 term: bn1+relu applied in A-staging. Y aliases X0 (t2 overwrites t1):
// safe, each block rewrites only the rows it staged, after the barriers.
#define LDA2 72
__global__ __launch_bounds__(256) void gemm2(const unsigned short* X0,
    const unsigned short* __restrict__ X1, const unsigned short* __restrict__ X2,
    const float* __restrict__ W, const float* __restrict__ bias,
    const float* __restrict__ gsumIn, const float* __restrict__ gamma,
    const float* __restrict__ beta, unsigned short* Y,
    float* __restrict__ gsumOut) {
  __shared__ unsigned short As[128 * LDA2];
  __shared__ unsigned short Bs[64 * LDA2];
  __shared__ float sred[128];
  __shared__ float scsh_s[128];   // [0..63]=sc, [64..127]=sh (bn1)
  int t = threadIdx.x;
  int row0 = blockIdx.x * 128;
  int b = (row0 >= VN) ? 1 : 0;
  int b2 = b * 2;
  int vb0 = row0 - b * VN;
  if (t < 128) sred[t] = 0.f;
  if (t >= 128 && t < 192) {
    int c = t - 128;
    float sc, sh;
    scsh_from8(gsumIn, 128, c, 64, gamma, beta, sc, sh);
    scsh_s[c] = sc; scsh_s[64 + c] = sh;
  }
  __syncthreads();
  int kk = (t & 15) * 4;    // k invariant across c8 (256 % 16 == 0)
  int r0 = t >> 4;
  float tsc[4], tsh[4];
  #pragma unroll
  for (int j = 0; j < 4; ++j) { tsc[j] = scsh_s[kk + j]; tsh[j] = scsh_s[64 + kk + j]; }
  int l = t & 63, wv = t >> 6;
  int lr = l & 15, q = l >> 4;
  int m0 = wv * 32;
  floatx4 acc[2][4];
  #pragma unroll
  for (int mi = 0; mi < 2; ++mi)
    #pragma unroll
    for (int ni = 0; ni < 4; ++ni) acc[mi][ni] = (floatx4)(0.f);

  #pragma unroll
  for (int term = 0; term < 3; ++term) {
    const unsigned short* Xp = (term == 0) ? X0 : (term == 1) ? X1 : X2;
    const float* Wt = W + term * 64 * 64;
    const unsigned short* srcBase =
        Xp + ((size_t)(b2 + (kk >> 5)) * VN + vb0) * 32 + (kk & 31);
    #pragma unroll
    for (int c8 = 0; c8 < 8; ++c8) {
      int row = c8 * 16 + r0;
      uint2 rawv = *(const uint2*)(srcBase + (size_t)row * 32);
      if (term == 0) {
        float y0 = fmaf(bflo(rawv.x), tsc[0], tsh[0]);
        float y1 = fmaf(bfhi(rawv.x), tsc[1], tsh[1]);
        float y2 = fmaf(bflo(rawv.y), tsc[2], tsh[2]);
        float y3 = fmaf(bfhi(rawv.y), tsc[3], tsh[3]);
        y0 = y0 > 0.f ? y0 : 0.f; y1 = y1 > 0.f ? y1 : 0.f;
        y2 = y2 > 0.f ? y2 : 0.f; y3 = y3 > 0.f ? y3 : 0.f;
        *(uint2*)(&As[row * LDA2 + kk]) = make_uint2(packbf(y0, y1), packbf(y2, y3));
      } else {
        *(uint2*)(&As[row * LDA2 + kk]) = rawv;
      }
    }
    #pragma unroll
    for (int c = 0; c < 16; ++c) {
      int f = c * 256 + t;
      int k = f >> 6, n = f & 63;
      Bs[n * LDA2 + k] = f2bf(Wt[f]);
    }
    __syncthreads();
    #pragma unroll
    for (int ks = 0; ks < 64; ks += 32) {
      bf16x8 af[2], bfr[4];
      #pragma unroll
      for (int mi = 0; mi < 2; ++mi)
        af[mi] = *(const bf16x8*)(&As[(m0 + mi * 16 + lr) * LDA2 + ks + q * 8]);
      #pragma unroll
      for (int ni = 0; ni < 4; ++ni)
        bfr[ni] = *(const bf16x8*)(&Bs[(ni * 16 + lr) * LDA2 + ks + q * 8]);
      #pragma unroll
      for (int mi = 0; mi < 2; ++mi)
        #pragma unroll
        for (int ni = 0; ni < 4; ++ni)
          acc[mi][ni] = __builtin_amdgcn_mfma_f32_16x16x32_bf16(af[mi], bfr[ni], acc[mi][ni], 0, 0, 0);
    }
    __syncthreads();
  }
  // epilogue: transpose through As (reuse) -> coalesced 16B stores
  #pragma unroll
  for (int ni = 0; ni < 4; ++ni) {
    int col = ni * 16 + lr;
    float bv = bias[col];
    float s = 0.f, s2 = 0.f;
    #pragma unroll
    for (int mi = 0; mi < 2; ++mi)
      #pragma unroll
      for (int r = 0; r < 4; ++r) {
        float y = acc[mi][ni][r] + bv;
        s += y; s2 += y * y;
        As[(m0 + mi * 16 + q * 4 + r) * TRS + col] = f2bf(y);
      }
    atomicAdd(&sred[col], s);
    atomicAdd(&sred[64 + col], s2);
  }
  __syncthreads();
  #pragma unroll
  for (int i = 0; i < 4; ++i) {
    int idx = i * 256 + t;
    int p = idx >> 9, rem = idx & 511;
    int rowIdx = rem >> 2, ch0 = (rem & 3) * 8;
    uint4 d = *(const uint4*)(&As[rowIdx * TRS + p * 32 + ch0]);
    *(uint4*)(Y + ((size_t)(b2 + p) * VN + vb0 + rowIdx) * 32 + ch0) = d;
  }
  if (t < 128) atomicAdd(&gsumOut[(blockIdx.x & 7) * 128 + t], sred[t]);
}

// ====== GEMM3: t3 = relu(bn2(t2)) @ W3 + b3  (two 64-col halves, y-grid) ===
__global__ __launch_bounds__(256) void gemm3(const unsigned short* __restrict__ X,
    const float* __restrict__ W, const float* __restrict__ bias,
    const float* __restrict__ gsumIn, const float* __restrict__ gamma,
    const float* __restrict__ beta, unsigned short* __restrict__ Y,
    float* __restrict__ gsumOut) {
  __shared__ unsigned short As[128 * LDA2];
  __shared__ unsigned short Bs[64 * LDA2];
  __shared__ float sred[128];
  __shared__ float scsh_s[128];   // bn2
  int t = threadIdx.x;
  int row0 = blockIdx.x * 128;
  int n0 = blockIdx.y * 64;
  int b = (row0 >= VN) ? 1 : 0;
  int b2 = b * 2;
  int vb0 = row0 - b * VN;
  if (t < 128) sred[t] = 0.f;
  if (t >= 128 && t < 192) {
    int c = t - 128;
    float sc, sh;
    scsh_from8(gsumIn, 128, c, 64, gamma, beta, sc, sh);
    scsh_s[c] = sc; scsh_s[64 + c] = sh;
  }
  __syncthreads();
  int kk = (t & 15) * 4;
  int r0 = t >> 4;
  float tsc[4], tsh[4];
  #pragma unroll
  for (int j = 0; j < 4; ++j) { tsc[j] = scsh_s[kk + j]; tsh[j] = scsh_s[64 + kk + j]; }
  const unsigned short* srcBase =
      X + ((size_t)(b2 + (kk >> 5)) * VN + vb0) * 32 + (kk & 31);
  #pragma unroll
  for (int c8 = 0; c8 < 8; ++c8) {
    int row = c8 * 16 + r0;
    uint2 rawv = *(const uint2*)(srcBase + (size_t)row * 32);
    float y0 = fmaf(bflo(rawv.x), tsc[0], tsh[0]);
    float y1 = fmaf(bfhi(rawv.x), tsc[1], tsh[1]);
    float y2 = fmaf(bflo(rawv.y), tsc[2], tsh[2]);
    float y3 = fmaf(bfhi(rawv.y), tsc[3], tsh[3]);
    y0 = y0 > 0.f ? y0 : 0.f; y1 = y1 > 0.f ? y1 : 0.f;
    y2 = y2 > 0.f ? y2 : 0.f; y3 = y3 > 0.f ? y3 : 0.f;
    *(uint2*)(&As[row * LDA2 + kk]) = make_uint2(packbf(y0, y1), packbf(y2, y3));
  }
  #pragma unroll
  for (int c = 0; c < 16; ++c) {
    int f = c * 256 + t;
    int k = f >> 6, n = f & 63;
    Bs[n * LDA2 + k] = f2bf(W[k * 128 + n0 + n]);
  }
  __syncthreads();
  int l = t & 63, wv = t >> 6;
  int lr = l & 15, q = l >> 4;
  int m0 = wv * 32;
  floatx4 acc[2][4];
  #pragma unroll
  for (int mi = 0; mi < 2; ++mi)
    #pragma unroll
    for (int ni = 0; ni < 4; ++ni) acc[mi][ni] = (floatx4)(0.f);
  #pragma unroll
  for (int ks = 0; ks < 64; ks += 32) {
    bf16x8 af[2], bfr[4];
    #pragma unroll
    for (int mi = 0; mi < 2; ++mi)
      af[mi] = *(const bf16x8*)(&As[(m0 + mi * 16 + lr) * LDA2 + ks + q * 8]);
    #pragma unroll
    for (int ni = 0; ni < 4; ++ni)
      bfr[ni] = *(const bf16x8*)(&Bs[(ni * 16 + lr) * LDA2 + ks + q * 8]);
    #pragma unroll
    for (int mi = 0; mi < 2; ++mi)
      #pragma unroll
      for (int ni = 0; ni < 4; ++ni)
        acc[mi][ni] = __builtin_amdgcn_mfma_f32_16x16x32_bf16(af[mi], bfr[ni], acc[mi][ni], 0, 0, 0);
  }
  __syncthreads();          // As reads done; reuse As as Tr[128][TRS]
  #pragma unroll
  for (int ni = 0; ni < 4; ++ni) {
    int lc = ni * 16 + lr;
    int col = n0 + lc;
    float bv = bias[col];
    float s = 0.f, s2 = 0.f;
    #pragma unroll
    for (int mi = 0; mi < 2; ++mi)
      #pragma unroll
      for (int r = 0; r < 4; ++r) {
        float y = acc[mi][ni][r] + bv;
        s += y; s2 += y * y;
        As[(m0 + mi * 16 + q * 4 + r) * TRS + lc] = f2bf(y);
      }
    atomicAdd(&sred[lc], s);
    atomicAdd(&sred[64 + lc], s2);
  }
  __syncthreads();
  #pragma unroll
  for (int i = 0; i < 4; ++i) {
    int idx = i * 256 + t;
    int rowIdx = idx >> 3, c0 = (idx & 7) * 8;
    uint4 d = *(const uint4*)(&As[rowIdx * TRS + c0]);
    *(uint4*)(Y + (size_t)(row0 + rowIdx) * 128 + n0 + c0) = d;
  }
  // gsumOut replica: [rep][0..127]=sums, [rep][128..255]=sumsq (128 channels)
  if (t < 128) {
    int lc = t & 63, p = t >> 6;
    atomicAdd(&gsumOut[(blockIdx.x & 7) * 256 + p * 128 + n0 + lc], sred[t]);
  }
}

// ---------------- final BN apply + ReLU, bf16 -> fp32 ----------------------
__global__ __launch_bounds__(256) void bn_apply_final(const unsigned short* __restrict__ T,
    float* __restrict__ Y, const float* __restrict__ gsum,
    const float* __restrict__ gamma, const float* __restrict__ beta) {
  __shared__ float scsh_s[256];   // [0..127]=sc, [128..255]=sh (bn3)
  int t = threadIdx.x;
  if (t < 128) {
    float sc, sh;
    scsh_from8(gsum, 256, t, 128, gamma, beta, sc, sh);
    scsh_s[t] = sc; scsh_s[128 + t] = sh;
  }
  __syncthreads();
  size_t i4 = ((size_t)blockIdx.x * 256 + t) * 4;
  int c0 = (int)(i4 & 127);
  ushort4 tv = *(const ushort4*)(T + i4);
  unsigned short sv[4] = {tv.x, tv.y, tv.z, tv.w};
  float ov[4];
  #pragma unroll
  for (int j = 0; j < 4; ++j) {
    int c = c0 + j;
    float y = fmaf(bf2f(sv[j]), scsh_s[c], scsh_s[128 + c]);
    ov[j] = y > 0.f ? y : 0.f;
  }
  *(float4*)(Y + i4) = make_float4(ov[0], ov[1], ov[2], ov[3]);
}

extern "C" void kernel_launch(void* const* d_in, const int* in_sizes, int n_in,
                              void* d_out, int out_size, void* d_ws, size_t ws_size,
                              hipStream_t stream) {
  const float* x    = (const float*)d_in[0];
  const int*   cols = (const int*)  d_in[2];
  const float* vals = (const float*)d_in[3];
  const float* W1   = (const float*)d_in[4];
  const float* b1   = (const float*)d_in[5];
  const float* g1   = (const float*)d_in[6];
  const float* be1  = (const float*)d_in[7];
  const float* W2   = (const float*)d_in[8];
  const float* b2   = (const float*)d_in[9];
  const float* g2   = (const float*)d_in[10];
  const float* be2  = (const float*)d_in[11];
  const float* W3   = (const float*)d_in[12];
  const float* b3   = (const float*)d_in[13];
  const float* g3   = (const float*)d_in[14];
  const float* be3  = (const float*)d_in[15];
  float* out = (float*)d_out;

  const size_t PL = (size_t)MROWS * 64;          // plane elements
  unsigned short* P0 = (unsigned short*)d_ws;    // t1, then t2
  unsigned short* P1 = P0 + PL;                  // x1
  unsigned short* P2 = P1 + PL;                  // x2, then t3 [MROWS,128]
  float* ctrl  = (float*)(P2 + 2 * PL);
  float* gsum1 = ctrl;                           // 8 x 128
  float* gsum2 = ctrl + 1024;                    // 8 x 128
  float* gsum3 = ctrl + 2048;                    // 8 x 256

  // zero stat accumulators (8 replicas each)
  hipMemsetAsync(ctrl, 0, 4096 * sizeof(float), stream);

  dim3 blk(256);
  int rowb = MROWS / 128;                        // 768
  int spmm_blocks = 3072;                        // 64 rows x 4 combos
  int ap128_blocks = (int)(PL * 2 / 4 / 256);    // 12288

  // Layer 1
  gemm1<<<rowb, blk, 0, stream>>>(x, W1, b1, P0, gsum1);

  // Layer 2 (K=3 Chebyshev); h1 = relu(bn1(t1)) applied inline everywhere
  spmm1<<<spmm_blocks, blk, 0, stream>>>(P0, cols, vals, gsum1, g1, be1, P1);
  spmm2<<<spmm_blocks, blk, 0, stream>>>(P1, P0, cols, vals, gsum1, g1, be1, P2);
  gemm2<<<rowb, blk, 0, stream>>>(P0, P1, P2, W2, b2, gsum1, g1, be1, P0, gsum2);

  // Layer 3; bn2-apply fused into gemm3 A-staging; two 64-col halves
  dim3 g3grid(rowb, 2);
  gemm3<<<g3grid, blk, 0, stream>>>(P0, W3, b3, gsum2, g2, be2, P2, gsum3);
  bn_apply_final<<<ap128_blocks, blk, 0, stream>>>(P2, out, gsum3, g3, be3);
}